// Round 1
// baseline (64.592 us; speedup 1.0000x reference)
//
#include <hip/hip_runtime.h>

#define BB 2
#define NN1 512
#define NN2 512
#define DD 128
#define TS 16
#define SXPAD 132   // row stride in floats: 16B-aligned, 132%32==4 -> rows shift banks

__device__ __forceinline__ float gelu_exact(float v) {
    return 0.5f * v * (1.0f + erff(v * 0.70710678118654752f));
}

// Kernel 1: per-row projection.
// rows [0, B*N1)          : hx[row][e] = b1[e] + sum_d x0[row,d]*Wa[d,e] + x[row,d]*Wb[d,e]
// rows [B*N1, B*N1+B*N2)  : hy[r][e]   = sum_d y[r,d]*Wc[d,e]
__global__ __launch_bounds__(128) void proj_kernel(
    const float* __restrict__ x0, const float* __restrict__ x,
    const float* __restrict__ y,  const float* __restrict__ W1,
    const float* __restrict__ b1, float* __restrict__ hx, float* __restrict__ hy) {
    const int row = blockIdx.x;
    const int e = threadIdx.x;
    __shared__ float r0[DD];
    __shared__ float r1[DD];
    const float* Wa = W1;
    const float* Wb = W1 + DD * DD;
    const float* Wc = W1 + 2 * DD * DD;

    if (row < BB * NN1) {
        r0[e] = x0[row * DD + e];
        r1[e] = x[row * DD + e];
        __syncthreads();
        float acc = b1[e];
        #pragma unroll 8
        for (int d = 0; d < DD; ++d) {
            acc += r0[d] * Wa[d * DD + e] + r1[d] * Wb[d * DD + e];
        }
        hx[row * DD + e] = acc;
    } else {
        const int r = row - BB * NN1;
        r0[e] = y[r * DD + e];
        __syncthreads();
        float acc = 0.0f;
        #pragma unroll 8
        for (int d = 0; d < DD; ++d) {
            acc += r0[d] * Wc[d * DD + e];
        }
        hy[r * DD + e] = acc;
    }
}

// Kernel 2: 16x16 (n,m) tile per block; out[b,n,m] = b2 + sum_e gelu(hx[n,e]+hy[m,e])*W2[e]
__global__ __launch_bounds__(256) void cross_kernel(
    const float* __restrict__ hx, const float* __restrict__ hy,
    const float* __restrict__ W2, const float* __restrict__ b2,
    float* __restrict__ out) {
    __shared__ float sx[TS][SXPAD];
    __shared__ float sy[TS][SXPAD];
    __shared__ float sw[DD];

    const int b  = blockIdx.z;
    const int n0 = blockIdx.y * TS;
    const int m0 = blockIdx.x * TS;
    const int tid = threadIdx.x;

    // Stage tiles: 16 rows x 128 floats each, as float4 (512 float4 per tile).
    for (int i = tid; i < TS * (DD / 4); i += 256) {
        const int r  = i >> 5;        // /32
        const int c4 = i & 31;        // %32
        *(float4*)&sx[r][c4 * 4] =
            *(const float4*)&hx[((b * NN1) + n0 + r) * DD + c4 * 4];
        *(float4*)&sy[r][c4 * 4] =
            *(const float4*)&hy[((b * NN2) + m0 + r) * DD + c4 * 4];
    }
    if (tid < DD) sw[tid] = W2[tid];
    __syncthreads();

    const int tn = tid >> 4;
    const int tm = tid & 15;

    float acc = b2[0];
    #pragma unroll 8
    for (int e4 = 0; e4 < DD / 4; ++e4) {
        const float4 a = *(const float4*)&sx[tn][e4 * 4];
        const float4 c = *(const float4*)&sy[tm][e4 * 4];
        const float4 w = *(const float4*)&sw[e4 * 4];
        acc += gelu_exact(a.x + c.x) * w.x;
        acc += gelu_exact(a.y + c.y) * w.y;
        acc += gelu_exact(a.z + c.z) * w.z;
        acc += gelu_exact(a.w + c.w) * w.w;
    }
    out[((b * NN1) + n0 + tn) * NN2 + m0 + tm] = acc;
}

extern "C" void kernel_launch(void* const* d_in, const int* in_sizes, int n_in,
                              void* d_out, int out_size, void* d_ws, size_t ws_size,
                              hipStream_t stream) {
    const float* x0 = (const float*)d_in[0];
    const float* x  = (const float*)d_in[1];
    const float* y  = (const float*)d_in[2];
    const float* W1 = (const float*)d_in[3];
    const float* b1 = (const float*)d_in[4];
    const float* W2 = (const float*)d_in[5];
    const float* b2 = (const float*)d_in[6];
    float* out = (float*)d_out;

    float* hx = (float*)d_ws;                 // B*N1*D floats = 512 KB
    float* hy = hx + (size_t)BB * NN1 * DD;   // B*N2*D floats = 512 KB

    proj_kernel<<<BB * (NN1 + NN2), 128, 0, stream>>>(x0, x, y, W1, b1, hx, hy);
    cross_kernel<<<dim3(NN2 / TS, NN1 / TS, BB), 256, 0, stream>>>(hx, hy, W2, b2, out);
}

// Round 2
// 42.752 us; speedup vs baseline: 1.5109x; 1.5109x over previous
//
#include <hip/hip_runtime.h>

#define BB 2
#define NN1 512
#define NN2 512
#define DD 128
#define TS 16
#define SXPAD 132   // row stride in floats: 16B-aligned, rows shift banks

// Fast tanh-approx GELU in sigmoid form:
// gelu(s) ~= s * sigmoid(s*(1.5957691 + 0.07135481*s^2))
//         =  s * rcp(1 + exp2(s*(-2.302118 - 0.102953*s^2)))
// max abs error vs exact ~1e-3; v_exp_f32 + v_rcp_f32 are quarter-rate HW ops.
__device__ __forceinline__ float gelu_fast(float s) {
    const float C1 = -2.3021181584f;   // -1.5957691216 * log2(e)
    const float C2 = -0.1029532929f;   // -0.0713548163 * log2(e)
    float t = s * s;
    float u = s * __builtin_fmaf(C2, t, C1);
    float e = __builtin_amdgcn_exp2f(u);
    float r = __builtin_amdgcn_rcpf(1.0f + e);
    return s * r;
}

// Kernel 1: per-row projection, 8 rows per block, 256 threads.
// Block-uniform x reads -> scalar loads; W reads coalesced across e (L1/L2).
#define PR 8
__global__ __launch_bounds__(256) void proj_kernel(
    const float* __restrict__ x0, const float* __restrict__ x,
    const float* __restrict__ y,  const float* __restrict__ W1,
    const float* __restrict__ b1, float* __restrict__ hx, float* __restrict__ hy) {
    const int e = threadIdx.x & (DD - 1);
    const int g = threadIdx.x >> 7;          // 0 or 1: row-half
    const int nxb = (BB * NN1) / PR;         // 128 blocks for hx
    const float* Wa = W1;
    const float* Wb = W1 + DD * DD;
    const float* Wc = W1 + 2 * DD * DD;

    if (blockIdx.x < nxb) {
        const int row0 = blockIdx.x * PR + g * (PR / 2);
        float acc0 = b1[e], acc1 = b1[e], acc2 = b1[e], acc3 = b1[e];
        #pragma unroll 4
        for (int d = 0; d < DD; ++d) {
            const float wa = Wa[d * DD + e];
            const float wb = Wb[d * DD + e];
            acc0 += x0[(row0 + 0) * DD + d] * wa + x[(row0 + 0) * DD + d] * wb;
            acc1 += x0[(row0 + 1) * DD + d] * wa + x[(row0 + 1) * DD + d] * wb;
            acc2 += x0[(row0 + 2) * DD + d] * wa + x[(row0 + 2) * DD + d] * wb;
            acc3 += x0[(row0 + 3) * DD + d] * wa + x[(row0 + 3) * DD + d] * wb;
        }
        hx[(row0 + 0) * DD + e] = acc0;
        hx[(row0 + 1) * DD + e] = acc1;
        hx[(row0 + 2) * DD + e] = acc2;
        hx[(row0 + 3) * DD + e] = acc3;
    } else {
        const int row0 = (blockIdx.x - nxb) * PR + g * (PR / 2);
        float acc0 = 0.f, acc1 = 0.f, acc2 = 0.f, acc3 = 0.f;
        #pragma unroll 4
        for (int d = 0; d < DD; ++d) {
            const float wc = Wc[d * DD + e];
            acc0 += y[(row0 + 0) * DD + d] * wc;
            acc1 += y[(row0 + 1) * DD + d] * wc;
            acc2 += y[(row0 + 2) * DD + d] * wc;
            acc3 += y[(row0 + 3) * DD + d] * wc;
        }
        hy[(row0 + 0) * DD + e] = acc0;
        hy[(row0 + 1) * DD + e] = acc1;
        hy[(row0 + 2) * DD + e] = acc2;
        hy[(row0 + 3) * DD + e] = acc3;
    }
}

// Kernel 2: 16x16 (n,m) tile per block; out[b,n,m] = b2 + sum_e gelu(hx[n,e]+hy[m,e])*W2[e]
__global__ __launch_bounds__(256) void cross_kernel(
    const float* __restrict__ hx, const float* __restrict__ hy,
    const float* __restrict__ W2, const float* __restrict__ b2,
    float* __restrict__ out) {
    __shared__ float sx[TS][SXPAD];
    __shared__ float sy[TS][SXPAD];
    __shared__ float sw[DD];

    const int b  = blockIdx.z;
    const int n0 = blockIdx.y * TS;
    const int m0 = blockIdx.x * TS;
    const int tid = threadIdx.x;

    for (int i = tid; i < TS * (DD / 4); i += 256) {
        const int r  = i >> 5;
        const int c4 = i & 31;
        *(float4*)&sx[r][c4 * 4] =
            *(const float4*)&hx[((b * NN1) + n0 + r) * DD + c4 * 4];
        *(float4*)&sy[r][c4 * 4] =
            *(const float4*)&hy[((b * NN2) + m0 + r) * DD + c4 * 4];
    }
    if (tid < DD) sw[tid] = W2[tid];
    __syncthreads();

    const int tn = tid >> 4;
    const int tm = tid & 15;

    float acc = b2[0];
    #pragma unroll 8
    for (int e4 = 0; e4 < DD / 4; ++e4) {
        const float4 a = *(const float4*)&sx[tn][e4 * 4];
        const float4 c = *(const float4*)&sy[tm][e4 * 4];
        const float4 w = *(const float4*)&sw[e4 * 4];
        acc += gelu_fast(a.x + c.x) * w.x;
        acc += gelu_fast(a.y + c.y) * w.y;
        acc += gelu_fast(a.z + c.z) * w.z;
        acc += gelu_fast(a.w + c.w) * w.w;
    }
    out[((b * NN1) + n0 + tn) * NN2 + m0 + tm] = acc;
}

extern "C" void kernel_launch(void* const* d_in, const int* in_sizes, int n_in,
                              void* d_out, int out_size, void* d_ws, size_t ws_size,
                              hipStream_t stream) {
    const float* x0 = (const float*)d_in[0];
    const float* x  = (const float*)d_in[1];
    const float* y  = (const float*)d_in[2];
    const float* W1 = (const float*)d_in[3];
    const float* b1 = (const float*)d_in[4];
    const float* W2 = (const float*)d_in[5];
    const float* b2 = (const float*)d_in[6];
    float* out = (float*)d_out;

    float* hx = (float*)d_ws;                 // B*N1*D floats = 512 KB
    float* hy = hx + (size_t)BB * NN1 * DD;   // B*N2*D floats = 512 KB

    const int nblocks = (BB * NN1) / PR + (BB * NN2) / PR;  // 256
    proj_kernel<<<nblocks, 256, 0, stream>>>(x0, x, y, W1, b1, hx, hy);
    cross_kernel<<<dim3(NN2 / TS, NN1 / TS, BB), 256, 0, stream>>>(hx, hy, W2, b2, out);
}

// Round 3
// 41.681 us; speedup vs baseline: 1.5497x; 1.0257x over previous
//
#include <hip/hip_runtime.h>

#define BB 2
#define NN1 512
#define NN2 512
#define DD 128
#define TS 32          // cross tile: 32x32 (n,m) per block
#define SXPAD 132      // row stride in floats: 16B-aligned, rows shift banks

// Fast tanh-approx GELU in sigmoid form:
// gelu(s) ~= s * sigmoid(s*(1.5957691 + 0.07135481*s^2))
//         =  s * rcp(1 + exp2(s*(-2.302118 - 0.102953*s^2)))
__device__ __forceinline__ float gelu_fast(float s) {
    const float C1 = -2.3021181584f;
    const float C2 = -0.1029532929f;
    float t = s * s;
    float u = s * __builtin_fmaf(C2, t, C1);
    float e = __builtin_amdgcn_exp2f(u);
    float r = __builtin_amdgcn_rcpf(1.0f + e);
    return s * r;
}

// Kernel 1: per-row projection, 8 rows per block, 256 threads.
#define PR 8
__global__ __launch_bounds__(256) void proj_kernel(
    const float* __restrict__ x0, const float* __restrict__ x,
    const float* __restrict__ y,  const float* __restrict__ W1,
    const float* __restrict__ b1, float* __restrict__ hx, float* __restrict__ hy) {
    const int e = threadIdx.x & (DD - 1);
    const int g = threadIdx.x >> 7;
    const int nxb = (BB * NN1) / PR;
    const float* Wa = W1;
    const float* Wb = W1 + DD * DD;
    const float* Wc = W1 + 2 * DD * DD;

    if (blockIdx.x < nxb) {
        const int row0 = blockIdx.x * PR + g * (PR / 2);
        float acc0 = b1[e], acc1 = b1[e], acc2 = b1[e], acc3 = b1[e];
        #pragma unroll 4
        for (int d = 0; d < DD; ++d) {
            const float wa = Wa[d * DD + e];
            const float wb = Wb[d * DD + e];
            acc0 += x0[(row0 + 0) * DD + d] * wa + x[(row0 + 0) * DD + d] * wb;
            acc1 += x0[(row0 + 1) * DD + d] * wa + x[(row0 + 1) * DD + d] * wb;
            acc2 += x0[(row0 + 2) * DD + d] * wa + x[(row0 + 2) * DD + d] * wb;
            acc3 += x0[(row0 + 3) * DD + d] * wa + x[(row0 + 3) * DD + d] * wb;
        }
        hx[(row0 + 0) * DD + e] = acc0;
        hx[(row0 + 1) * DD + e] = acc1;
        hx[(row0 + 2) * DD + e] = acc2;
        hx[(row0 + 3) * DD + e] = acc3;
    } else {
        const int row0 = (blockIdx.x - nxb) * PR + g * (PR / 2);
        float acc0 = 0.f, acc1 = 0.f, acc2 = 0.f, acc3 = 0.f;
        #pragma unroll 4
        for (int d = 0; d < DD; ++d) {
            const float wc = Wc[d * DD + e];
            acc0 += y[(row0 + 0) * DD + d] * wc;
            acc1 += y[(row0 + 1) * DD + d] * wc;
            acc2 += y[(row0 + 2) * DD + d] * wc;
            acc3 += y[(row0 + 3) * DD + d] * wc;
        }
        hy[(row0 + 0) * DD + e] = acc0;
        hy[(row0 + 1) * DD + e] = acc1;
        hy[(row0 + 2) * DD + e] = acc2;
        hy[(row0 + 3) * DD + e] = acc3;
    }
}

// Kernel 2: 32x32 (n,m) tile per block, 2x2 outputs per thread.
// out[b,n,m] = b2 + sum_e gelu(hx[n,e]+hy[m,e])*W2[e]
__global__ __launch_bounds__(256) void cross_kernel(
    const float* __restrict__ hx, const float* __restrict__ hy,
    const float* __restrict__ W2, const float* __restrict__ b2,
    float* __restrict__ out) {
    __shared__ float sx[TS][SXPAD];
    __shared__ float sy[TS][SXPAD];
    __shared__ float sw[DD];

    const int b  = blockIdx.z;
    const int n0 = blockIdx.y * TS;
    const int m0 = blockIdx.x * TS;
    const int tid = threadIdx.x;

    // Stage: 32 rows x 128 floats per tile = 1024 float4 each; 4 iters/thread.
    for (int i = tid; i < TS * (DD / 4); i += 256) {
        const int r  = i >> 5;
        const int c4 = i & 31;
        *(float4*)&sx[r][c4 * 4] =
            *(const float4*)&hx[((b * NN1) + n0 + r) * DD + c4 * 4];
        *(float4*)&sy[r][c4 * 4] =
            *(const float4*)&hy[((b * NN2) + m0 + r) * DD + c4 * 4];
    }
    if (tid < DD) sw[tid] = W2[tid];
    __syncthreads();

    const int tn = (tid >> 4) * 2;   // row pair: rows tn, tn+1
    const int tm = (tid & 15) * 2;   // col pair: cols tm, tm+1

    float acc00 = 0.f, acc01 = 0.f, acc10 = 0.f, acc11 = 0.f;

    #pragma unroll 4
    for (int e4 = 0; e4 < DD / 4; ++e4) {
        const float4 a0 = *(const float4*)&sx[tn][e4 * 4];
        const float4 a1 = *(const float4*)&sx[tn + 1][e4 * 4];
        const float4 c0 = *(const float4*)&sy[tm][e4 * 4];
        const float4 c1 = *(const float4*)&sy[tm + 1][e4 * 4];
        const float4 w  = *(const float4*)&sw[e4 * 4];

        acc00 += gelu_fast(a0.x + c0.x) * w.x;
        acc01 += gelu_fast(a0.x + c1.x) * w.x;
        acc10 += gelu_fast(a1.x + c0.x) * w.x;
        acc11 += gelu_fast(a1.x + c1.x) * w.x;

        acc00 += gelu_fast(a0.y + c0.y) * w.y;
        acc01 += gelu_fast(a0.y + c1.y) * w.y;
        acc10 += gelu_fast(a1.y + c0.y) * w.y;
        acc11 += gelu_fast(a1.y + c1.y) * w.y;

        acc00 += gelu_fast(a0.z + c0.z) * w.z;
        acc01 += gelu_fast(a0.z + c1.z) * w.z;
        acc10 += gelu_fast(a1.z + c0.z) * w.z;
        acc11 += gelu_fast(a1.z + c1.z) * w.z;

        acc00 += gelu_fast(a0.w + c0.w) * w.w;
        acc01 += gelu_fast(a0.w + c1.w) * w.w;
        acc10 += gelu_fast(a1.w + c0.w) * w.w;
        acc11 += gelu_fast(a1.w + c1.w) * w.w;
    }

    const float bias = b2[0];
    float* o0 = &out[((size_t)(b * NN1) + n0 + tn) * NN2 + m0 + tm];
    float* o1 = o0 + NN2;
    *(float2*)o0 = make_float2(acc00 + bias, acc01 + bias);
    *(float2*)o1 = make_float2(acc10 + bias, acc11 + bias);
}

extern "C" void kernel_launch(void* const* d_in, const int* in_sizes, int n_in,
                              void* d_out, int out_size, void* d_ws, size_t ws_size,
                              hipStream_t stream) {
    const float* x0 = (const float*)d_in[0];
    const float* x  = (const float*)d_in[1];
    const float* y  = (const float*)d_in[2];
    const float* W1 = (const float*)d_in[3];
    const float* b1 = (const float*)d_in[4];
    const float* W2 = (const float*)d_in[5];
    const float* b2 = (const float*)d_in[6];
    float* out = (float*)d_out;

    float* hx = (float*)d_ws;
    float* hy = hx + (size_t)BB * NN1 * DD;

    const int nblocks = (BB * NN1) / PR + (BB * NN2) / PR;
    proj_kernel<<<nblocks, 256, 0, stream>>>(x0, x, y, W1, b1, hx, hy);
    cross_kernel<<<dim3(NN2 / TS, NN1 / TS, BB), 256, 0, stream>>>(hx, hy, W2, b2, out);
}